// Round 1
// baseline (553.068 us; speedup 1.0000x reference)
//
#include <hip/hip_runtime.h>

// Problem constants (B,H,L,D)=(8,12,1024,768), K=512
constexpr int B = 8;
constexpr int H = 12;
constexpr int L = 1024;
constexpr int D = 768;
constexpr int K = 512;

constexpr int ROWS   = H * L;          // 12288 rows per batch (h,i flattened)
constexpr int NCHUNK = 96;             // partial chunks per batch
constexpr int CHUNK  = ROWS / NCHUNK;  // 128 rows per chunk
constexpr int GROUPS = 16;             // second-level reduction groups
constexpr int GCH    = NCHUNK / GROUPS; // 6 chunks per group

typedef float v2f __attribute__((ext_vector_type(2)));

// ---------------------------------------------------------------------------
// Kernel 1: deterministic partial column sums of scores.
// grid = B*NCHUNK = 768 blocks, 512 threads (8 waves/block -> 24 waves/CU).
// Thread t owns columns 2t..2t+1 (float2). Each block sums CHUNK=128
// contiguous rows sequentially -> partial[b][chunk][0..L).
// NOTE: per-column summation order is IDENTICAL to the verified 256-thread
// float4 version (same 128-row sequential chain) — only lane->column width
// changed, doubling resident waves for latency hiding.
// ---------------------------------------------------------------------------
__global__ __launch_bounds__(512) void colsum_partial_kernel(
    const float* __restrict__ scores, float* __restrict__ partial) {
    const int bc = blockIdx.x;
    const int b = bc / NCHUNK;
    const int c = bc % NCHUNK;
    const int t = threadIdx.x;  // 0..511 -> float2 column index

    const v2f* src = (const v2f*)(scores + (size_t)b * ROWS * L)
                     + (size_t)(c * CHUNK) * (L / 2) + t;
    v2f acc; acc.x = 0.f; acc.y = 0.f;
#pragma unroll 16
    for (int r = 0; r < CHUNK; ++r) {
        v2f v = __builtin_nontemporal_load(&src[(size_t)r * (L / 2)]);
        acc.x += v.x; acc.y += v.y;
    }
    ((v2f*)(partial + (size_t)(b * NCHUNK + c) * L))[t] = acc;
}

// ---------------------------------------------------------------------------
// Kernel 1b: wide second-level reduction partial(96) -> partial2(16 groups).
// grid = B*GROUPS*L/256 = 512 blocks, 256 threads. Fixes the 8-block
// latency-bound reduction that used to live entirely inside the topk kernel.
// Group g sums chunks [g*GCH, g*GCH+GCH) sequentially (deterministic).
// ---------------------------------------------------------------------------
__global__ __launch_bounds__(256) void reduce2_kernel(
    const float* __restrict__ partial, float* __restrict__ partial2) {
    const int tid = blockIdx.x * 256 + threadIdx.x;  // 0 .. B*GROUPS*L-1
    const int b   = tid >> 14;           // / (GROUPS*L)
    const int rem = tid & (GROUPS * L - 1);
    const int g   = rem >> 10;           // / L
    const int j   = rem & (L - 1);

    const float* p = partial + ((size_t)b * NCHUNK + g * GCH) * L + j;
    float s = 0.f;
#pragma unroll
    for (int k = 0; k < GCH; ++k) s += p[(size_t)k * L];
    partial2[tid] = s;
}

// ---------------------------------------------------------------------------
// Kernel 2: reduce 16 group-partials -> importance, then top-K by rank
// counting, compact selected indices ascending (== jnp.sort(top_k idx)).
// grid = B blocks, 1024 threads (thread j owns column j).
// Tie-break matches jax.lax.top_k: larger value first; equal -> lower idx.
// ---------------------------------------------------------------------------
__global__ __launch_bounds__(1024) void topk_kernel(
    const float* __restrict__ partial2, int* __restrict__ idx_out) {
    const int b = blockIdx.x;
    const int j = threadIdx.x;  // 0..1023

    __shared__ float v[L];
    __shared__ int wave_tot[16];
    __shared__ int wave_pref[16];

    // Deterministic fixed-order reduction of the 16 group partials.
    const float* p = partial2 + (size_t)b * GROUPS * L + j;
    float s = 0.f;
#pragma unroll
    for (int g = 0; g < GROUPS; ++g) s += p[(size_t)g * L];
    const float val = s * (1.0f / (float)H);
    v[j] = val;
    __syncthreads();

    // rank = #elements strictly greater, or equal with smaller index.
    // LDS read vectorized as float4 (broadcast, conflict-free).
    int rank = 0;
    const float4* v4 = (const float4*)v;
    for (int q = 0; q < L / 4; ++q) {
        float4 u = v4[q];
        const int base = q * 4;
        rank += (u.x > val) || (u.x == val && (base + 0) < j);
        rank += (u.y > val) || (u.y == val && (base + 1) < j);
        rank += (u.z > val) || (u.z == val && (base + 2) < j);
        rank += (u.w > val) || (u.w == val && (base + 3) < j);
    }
    const bool sel = (rank < K);

    // Block-wide compaction: ballot within wave + cross-wave scan.
    const int lane = j & 63;
    const int wave = j >> 6;
    unsigned long long ball = __ballot(sel);
    int within = __popcll(ball & ((1ull << lane) - 1ull));
    if (lane == 0) wave_tot[wave] = __popcll(ball);
    __syncthreads();
    if (j == 0) {
        int run = 0;
        for (int w = 0; w < 16; ++w) { wave_pref[w] = run; run += wave_tot[w]; }
    }
    __syncthreads();
    if (sel) idx_out[b * K + wave_pref[wave] + within] = j;
}

// ---------------------------------------------------------------------------
// Kernel 3: gather rows + mask. grid = B*(K+1) blocks, 192 threads (float4/row).
// Output layout: final_token [B][K+1][D] then final_mask [B][K+1].
// ---------------------------------------------------------------------------
__global__ __launch_bounds__(192) void gather_kernel(
    const float* __restrict__ hidden, const float* __restrict__ amask,
    const int* __restrict__ idx, float* __restrict__ out) {
    const int m = blockIdx.x;        // 0..B*(K+1)-1
    const int b = m / (K + 1);
    const int r = m % (K + 1);
    const int src = (r == 0) ? 0 : idx[b * K + r - 1];

    const float4* srow = (const float4*)(hidden + (size_t)(b * L + src) * D);
    float4* drow = (float4*)(out + (size_t)m * D);
    drow[threadIdx.x] = srow[threadIdx.x];

    if (threadIdx.x == 0) {
        float mv = (r == 0) ? 0.0f : amask[b * L + src];
        out[(size_t)B * (K + 1) * D + m] = mv;
    }
}

extern "C" void kernel_launch(void* const* d_in, const int* in_sizes, int n_in,
                              void* d_out, int out_size, void* d_ws, size_t ws_size,
                              hipStream_t stream) {
    const float* hidden = (const float*)d_in[0];  // (B, L, D) fp32
    const float* amask  = (const float*)d_in[1];  // (B, 1, 1, L) fp32
    const float* scores = (const float*)d_in[2];  // (B, H, L, L) fp32
    float* out = (float*)d_out;

    // Workspace layout (unchanged vs verified kernel: 3 MB + 16 KB):
    float* partial = (float*)d_ws;                                   // B*NCHUNK*L fp32 (3 MB)
    int*   idx     = (int*)((char*)d_ws +
                            (size_t)B * NCHUNK * L * sizeof(float)); // B*K ints (16 KB)
    // partial2 (B*GROUPS*L fp32 = 512 KB) is stashed at the START of d_out:
    // gather_kernel runs last and overwrites every byte of d_out, so this
    // scratch aliasing is safe (out_size = 12.6 MB >> 512 KB).
    float* partial2 = out;

    colsum_partial_kernel<<<B * NCHUNK, 512, 0, stream>>>(scores, partial);
    reduce2_kernel<<<(B * GROUPS * L) / 256, 256, 0, stream>>>(partial, partial2);
    topk_kernel<<<B, 1024, 0, stream>>>(partial2, idx);
    gather_kernel<<<B * (K + 1), 192, 0, stream>>>(hidden, amask, idx, out);
}